// Round 2
// 1125.249 us; speedup vs baseline: 1.0322x; 1.0322x over previous
//
#include <hip/hip_runtime.h>
#include <hip/hip_bf16.h>

#define NGRP 15552                 // B*L = 64*243
#define RROWS 264384               // NGRP*17  (= 4131 * 64)
#define EPSV 1e-5f

typedef __attribute__((ext_vector_type(8))) short s16x8;
typedef __attribute__((ext_vector_type(4))) float f32x4;
typedef __hip_bfloat16 bf16;

__device__ __forceinline__ float bf2f(unsigned short u) {
    union { unsigned int i; float f; } x; x.i = ((unsigned int)u) << 16; return x.f;
}
__device__ __forceinline__ unsigned short f2bf(float f) {
    bf16 b = __float2bfloat16(f);
    return *reinterpret_cast<unsigned short*>(&b);
}

// ---------------- K0: weight prep (verified round-0) ----------------
__global__ __launch_bounds__(256)
void k_prep(const float* __restrict__ w1, const float* __restrict__ b1,
            const float* __restrict__ w2, const float* __restrict__ b2,
            const float* __restrict__ mw1, const float* __restrict__ mw2,
            const float* __restrict__ adj,
            bf16* __restrict__ wsum, bf16* __restrict__ w1m, bf16* __restrict__ w2m,
            float* __restrict__ bsum, float* __restrict__ srow, float* __restrict__ stats)
{
    const int idx = blockIdx.x * 256 + threadIdx.x;      // grid = 512 blocks -> 131072
    if (idx < 65536) wsum[idx] = __float2bfloat16(w1[idx] + w2[idx]);
    w1m[idx] = __float2bfloat16(mw1[idx]);               // 131072 elements exactly
    w2m[idx] = __float2bfloat16(mw2[idx]);
    if (idx < 256) bsum[idx] = b1[idx] + b2[idx];
    if (idx < 512) stats[idx] = 0.0f;                    // re-zeroed every launch
    if (idx < 17) {
        float s = 0.0f;
        for (int j = 0; j < 17; ++j) s += adj[idx * 17 + j];
        srow[idx] = s;
    }
}

// ---------------- K1: xa[n,i,:] = sum_j adj[i,j] x[n,j,:] (verified) ----------
__global__ __launch_bounds__(256)
void k_agg(const float* __restrict__ x, const float* __restrict__ adj,
           bf16* __restrict__ xa)
{
    __shared__ float sadj[289];
    const int t = threadIdx.x;
    sadj[t < 289 ? t : 0] = adj[t < 289 ? t : 0];
    if (t < 33) sadj[256 + t] = adj[256 + t];
    __syncthreads();
    const size_t base = (size_t)blockIdx.x * (17 * 256) + t;
    float xv[17];
#pragma unroll
    for (int j = 0; j < 17; ++j) xv[j] = x[base + j * 256];
#pragma unroll
    for (int i = 0; i < 17; ++i) {
        float s = 0.0f;
#pragma unroll
        for (int j = 0; j < 17; ++j) s = fmaf(sadj[i * 17 + j], xv[j], s);
        xa[base + i * 256] = __float2bfloat16(s);
    }
}

// ---------------- GEMM-H: h = relu(xa @ wsum^T + srow*bsum) --------------------
// M = RROWS, N = 256, K = 256. Values bit-identical to round-0 gemm_bt<256,0>;
// only the store path changed: LDS restage -> full 128B-line global writes.
__global__ __launch_bounds__(256, 2)
void gemm_h(const bf16* __restrict__ A, const bf16* __restrict__ Bw,
            bf16* __restrict__ H, const float* __restrict__ bias,
            const float* __restrict__ srow)
{
    constexpr int LDK = 72;                    // staging row stride (bf16)
    constexpr int LDC = 136;                   // epilogue tile stride (bf16)
    __shared__ char smem[2 * 128 * LDK * 2];   // 36864 B; epilogue overlays sC
    bf16* const sA = (bf16*)smem;
    bf16* const sB = sA + 128 * LDK;
    bf16* const sC = (bf16*)smem;              // 128*136*2 = 34816 B <= 36864

    const int tid  = threadIdx.x;
    const int wave = tid >> 6, lane = tid & 63;
    const int wm = (wave >> 1) * 64, wn = (wave & 1) * 64;
    const int quad = lane >> 4, l16 = lane & 15;
    const int m0 = blockIdx.y * 128;
    const int n0 = blockIdx.x * 128;

    f32x4 acc[4][4] = {};
    const int str = tid >> 3;
    const int stc = (tid & 7) * 8;

    for (int kt = 0; kt < 4; ++kt) {           // K = 256
        const int k0 = kt * 64;
#pragma unroll
        for (int i = 0; i < 4; ++i) {
            const int r = str + i * 32;
            int gr = m0 + r; gr = gr < RROWS ? gr : RROWS - 1;
            *(uint4*)(sA + r * LDK + stc) =
                *(const uint4*)(A + (size_t)gr * 256 + k0 + stc);
        }
#pragma unroll
        for (int i = 0; i < 4; ++i) {
            const int r = str + i * 32;
            *(uint4*)(sB + r * LDK + stc) =
                *(const uint4*)(Bw + (size_t)(n0 + r) * 256 + k0 + stc);
        }
        __syncthreads();
#pragma unroll
        for (int ks = 0; ks < 2; ++ks) {
            const int kk = ks * 32 + quad * 8;
            s16x8 af[4], bfr[4];
#pragma unroll
            for (int x = 0; x < 4; ++x)
                af[x] = *(const s16x8*)(sA + (wm + x * 16 + l16) * LDK + kk);
#pragma unroll
            for (int x = 0; x < 4; ++x)
                bfr[x] = *(const s16x8*)(sB + (wn + x * 16 + l16) * LDK + kk);
#pragma unroll
            for (int i = 0; i < 4; ++i)
#pragma unroll
                for (int j = 0; j < 4; ++j)
                    acc[i][j] = __builtin_amdgcn_mfma_f32_16x16x32_bf16(
                        af[i], bfr[j], acc[i][j], 0, 0, 0);
        }
        __syncthreads();
    }

    // ---- epilogue: bias + relu -> sC (bf16) ----
#pragma unroll
    for (int j = 0; j < 4; ++j) {
        const int cl = wn + j * 16 + l16;
        const float bc = bias[n0 + cl];
#pragma unroll
        for (int i = 0; i < 4; ++i) {
#pragma unroll
            for (int r = 0; r < 4; ++r) {
                const int lr = wm + i * 16 + quad * 4 + r;
                const int gr = m0 + lr;
                float v = acc[i][j][r] + srow[gr % 17] * bc;
                v = fmaxf(v, 0.0f);
                sC[lr * LDC + cl] = __float2bfloat16(v);
            }
        }
    }
    __syncthreads();
    // ---- coalesced write-back: 16B/lane, full cache lines ----
    const int row = tid >> 1;                           // 0..127
    const int cb  = (tid & 1) * 64;                     // bf16 chunk within 128 cols
    if (m0 + row < RROWS) {
#pragma unroll
        for (int k = 0; k < 8; ++k) {
            uint4 u = *(const uint4*)(sC + row * LDC + cb + k * 8);
            *(uint4*)(H + (size_t)(m0 + row) * 256 + n0 + cb + k * 8) = u;
        }
    }
}

// ---------------- K2.5: per-channel sum / sumsq (verified round-0) -------------
__global__ __launch_bounds__(256)
void k_stats(const bf16* __restrict__ h, float* __restrict__ stats)
{
    const int t  = threadIdx.x;
    const int c0 = (t & 127) * 2;
    const int rs = t >> 7;
    float s0 = 0, s1 = 0, q0 = 0, q1 = 0;
    for (int r = blockIdx.x * 2 + rs; r < RROWS; r += 1024) {   // grid = 512 blocks
        const ushort2 u = *(const ushort2*)(h + (size_t)r * 256 + c0);
        const float v0 = bf2f(u.x), v1 = bf2f(u.y);
        s0 += v0; q0 += v0 * v0;
        s1 += v1; q1 += v1 * v1;
    }
    atomicAdd(&stats[c0], s0);
    atomicAdd(&stats[c0 + 1], s1);
    atomicAdd(&stats[256 + c0], q0);
    atomicAdd(&stats[256 + c0 + 1], q1);
}

// ---------------- K3: BN + LN -> bf16 (verified round-0) -----------------------
__global__ __launch_bounds__(256)
void k_norm(const bf16* __restrict__ h, bf16* __restrict__ hn,
            const float* __restrict__ stats,
            const float* __restrict__ bng, const float* __restrict__ bnb,
            const float* __restrict__ lng, const float* __restrict__ lnb)
{
    __shared__ float sm[256], sv[256], sg[256], sb[256], sl[256], so[256];
    const int t = threadIdx.x;
    {
        const float mu  = stats[t] * (1.0f / RROWS);
        const float var = stats[256 + t] * (1.0f / RROWS) - mu * mu;
        sm[t] = mu; sv[t] = rsqrtf(var + EPSV);
        sg[t] = bng[t]; sb[t] = bnb[t]; sl[t] = lng[t]; so[t] = lnb[t];
    }
    __syncthreads();
    const int wave = t >> 6, lane = t & 63;
    const int c = lane * 4;
    float mn[4], rs[4], gg[4], bb[4], lg[4], lb[4];
#pragma unroll
    for (int k = 0; k < 4; ++k) {
        mn[k] = sm[c + k]; rs[k] = sv[c + k]; gg[k] = sg[c + k];
        bb[k] = sb[c + k]; lg[k] = sl[c + k]; lb[k] = so[c + k];
    }
    for (int row = blockIdx.x * 4 + wave; row < RROWS; row += 8192) { // grid = 2048
        const ushort4 u = *(const ushort4*)(h + (size_t)row * 256 + c);
        float v[4] = { bf2f(u.x), bf2f(u.y), bf2f(u.z), bf2f(u.w) };
        float s = 0.0f, q = 0.0f;
#pragma unroll
        for (int k = 0; k < 4; ++k) {
            v[k] = (v[k] - mn[k]) * rs[k] * gg[k] + bb[k];
            s += v[k]; q += v[k] * v[k];
        }
#pragma unroll
        for (int off = 32; off > 0; off >>= 1) {
            s += __shfl_xor(s, off);
            q += __shfl_xor(q, off);
        }
        const float lmu = s * (1.0f / 256.0f);
        const float lrs = rsqrtf(q * (1.0f / 256.0f) - lmu * lmu + EPSV);
        ushort4 o;
        o.x = f2bf((v[0] - lmu) * lrs * lg[0] + lb[0]);
        o.y = f2bf((v[1] - lmu) * lrs * lg[1] + lb[1]);
        o.z = f2bf((v[2] - lmu) * lrs * lg[2] + lb[2]);
        o.w = f2bf((v[3] - lmu) * lrs * lg[3] + lb[3]);
        *(ushort4*)(hn + (size_t)row * 256 + c) = o;
    }
}

// ---------------- K_MLP2: fc1 -> relu -> LDS mid -> fc2 (+bias) ----------------
// One block = 64 rows (RROWS = 4131*64 exactly). mid never touches global.
__global__ __launch_bounds__(256, 2)
void k_mlp2(const bf16* __restrict__ hng, const bf16* __restrict__ w1m,
            const float* __restrict__ mb1, const bf16* __restrict__ w2m,
            const float* __restrict__ mb2, float* __restrict__ out)
{
    constexpr int LDH = 264;                 // bf16 row stride: 528B
    constexpr int LDO = 260;                 // f32 row stride: 1040B
    __shared__ char smemB[64 * LDH * 2 * 2]; // 67584 B: [hn | mid]; overlaid by oc
    bf16* const hn  = (bf16*)smemB;
    bf16* const mid = hn + 64 * LDH;
    float* const oc = (float*)smemB;         // 64*260*4 = 66560 B <= 67584

    const int tid  = threadIdx.x;
    const int wave = tid >> 6, lane = tid & 63;
    const int quad = lane >> 4, l16 = lane & 15;
    const int m0 = blockIdx.x * 64;

    // ---- stage hn tile: 4 threads per row, 8 x uint4 each ----
    {
        const int r = tid >> 2, c = (tid & 3) * 64;
        const bf16* src = hng + (size_t)(m0 + r) * 256 + c;
#pragma unroll
        for (int k = 0; k < 8; ++k)
            *(uint4*)(hn + r * LDH + c + k * 8) = *(const uint4*)(src + k * 8);
    }
    __syncthreads();

    // ---- wave owns 64 output cols (wn); K split in two halves of 256 ----
    const int wn = wave * 64;
    f32x4 aco[4][4] = {};                     // fc2 accumulator across halves

    for (int hh = 0; hh < 2; ++hh) {
        // stage 1: acm = hn @ w1m[hh*256 + wn .. +64, :]^T  (B streamed from L2)
        f32x4 acm[4][4] = {};
#pragma unroll 2
        for (int ks = 0; ks < 8; ++ks) {
            const int kk = ks * 32 + quad * 8;
            s16x8 af[4], bw[4];
#pragma unroll
            for (int j = 0; j < 4; ++j)
                bw[j] = *(const s16x8*)(w1m + (size_t)(hh * 256 + wn + j * 16 + l16) * 256 + kk);
#pragma unroll
            for (int i = 0; i < 4; ++i)
                af[i] = *(const s16x8*)(hn + (i * 16 + l16) * LDH + kk);
#pragma unroll
            for (int i = 0; i < 4; ++i)
#pragma unroll
                for (int j = 0; j < 4; ++j)
                    acm[i][j] = __builtin_amdgcn_mfma_f32_16x16x32_bf16(
                        af[i], bw[j], acm[i][j], 0, 0, 0);
        }
        __syncthreads();                      // prior stage-2 reads of mid complete
        // relu + bias -> mid (LDS, bf16)
#pragma unroll
        for (int j = 0; j < 4; ++j) {
            const int cl = wn + j * 16 + l16;
            const float bc = mb1[hh * 256 + cl];
#pragma unroll
            for (int i = 0; i < 4; ++i)
#pragma unroll
                for (int r = 0; r < 4; ++r) {
                    float v = acm[i][j][r] + bc;
                    mid[(i * 16 + quad * 4 + r) * LDH + cl] =
                        __float2bfloat16(fmaxf(v, 0.0f));
                }
        }
        __syncthreads();
        // stage 2: aco += mid @ w2m[wn.., hh*256..]^T
#pragma unroll 2
        for (int ks = 0; ks < 8; ++ks) {
            const int kk = ks * 32 + quad * 8;
            s16x8 af[4], bw[4];
#pragma unroll
            for (int j = 0; j < 4; ++j)
                bw[j] = *(const s16x8*)(w2m + (size_t)(wn + j * 16 + l16) * 512 + hh * 256 + kk);
#pragma unroll
            for (int i = 0; i < 4; ++i)
                af[i] = *(const s16x8*)(mid + (i * 16 + l16) * LDH + kk);
#pragma unroll
            for (int i = 0; i < 4; ++i)
#pragma unroll
                for (int j = 0; j < 4; ++j)
                    aco[i][j] = __builtin_amdgcn_mfma_f32_16x16x32_bf16(
                        af[i], bw[j], aco[i][j], 0, 0, 0);
        }
        __syncthreads();                      // mid free for next half / epilogue
    }

    // ---- epilogue: + mb2, stage fp32 tile in LDS, coalesced dwordx4 stores ----
#pragma unroll
    for (int j = 0; j < 4; ++j) {
        const int cl = wn + j * 16 + l16;
        const float bc = mb2[cl];
#pragma unroll
        for (int i = 0; i < 4; ++i)
#pragma unroll
            for (int r = 0; r < 4; ++r)
                oc[(i * 16 + quad * 4 + r) * LDO + cl] = aco[i][j][r] + bc;
    }
    __syncthreads();
    const int row = tid >> 2;                 // 0..63
    const int cb2 = (tid & 3) * 64;           // f32 chunk
    const size_t gb = (size_t)(m0 + row) * 256 + cb2;
#pragma unroll
    for (int k = 0; k < 16; ++k) {
        f32x4 u = *(const f32x4*)(oc + row * LDO + cb2 + k * 4);
        *(f32x4*)(out + gb + k * 4) = u;
    }
}

extern "C" void kernel_launch(void* const* d_in, const int* in_sizes, int n_in,
                              void* d_out, int out_size, void* d_ws, size_t ws_size,
                              hipStream_t stream)
{
    const float* x   = (const float*)d_in[0];
    const float* adj = (const float*)d_in[1];
    const float* w1  = (const float*)d_in[2];
    const float* b1  = (const float*)d_in[3];
    const float* w2  = (const float*)d_in[4];
    const float* b2  = (const float*)d_in[5];
    const float* bng = (const float*)d_in[6];
    const float* bnb = (const float*)d_in[7];
    const float* lng = (const float*)d_in[8];
    const float* lnb = (const float*)d_in[9];
    const float* mw1 = (const float*)d_in[10];
    const float* mb1 = (const float*)d_in[11];
    const float* mw2 = (const float*)d_in[12];
    const float* mb2 = (const float*)d_in[13];

    char* ws = (char*)d_ws;
    const size_t SZ1 = (size_t)RROWS * 256 * 2;          // 135,364,608 B
    bf16* xa = (bf16*)(ws);                              // xa, later reused as hn
    bf16* h  = (bf16*)(ws + SZ1);                        // stage-1 output
    char* wp = ws + 2 * SZ1;
    bf16*  wsum  = (bf16*)(wp);
    bf16*  w1m   = (bf16*)(wp + 131072);
    bf16*  w2m   = (bf16*)(wp + 131072 + 262144);
    float* bsum  = (float*)(wp + 131072 + 262144 + 262144);
    float* srow  = (float*)((char*)bsum + 1024);
    float* stats = (float*)((char*)srow + 128);

    k_prep<<<512, 256, 0, stream>>>(w1, b1, w2, b2, mw1, mw2, adj,
                                    wsum, w1m, w2m, bsum, srow, stats);
    k_agg<<<NGRP, 256, 0, stream>>>(x, adj, xa);
    gemm_h<<<dim3(2, 2066), 256, 0, stream>>>(xa, wsum, h, bsum, srow);
    k_stats<<<512, 256, 0, stream>>>(h, stats);
    k_norm<<<2048, 256, 0, stream>>>(h, xa, stats, bng, bnb, lng, lnb);  // hn -> xa
    k_mlp2<<<RROWS / 64, 256, 0, stream>>>(xa, w1m, mb1, w2m, mb2, (float*)d_out);
}